// Round 1
// 481.971 us; speedup vs baseline: 1.0454x; 1.0454x over previous
//
#include <hip/hip_runtime.h>

// Problem constants: B=32, DIM=512, C=128, NH=4, HD=32, WS=14, N=196, H_IN=56
#define QSCALE 0.17677669529663687f   // 32^-0.5

// ---------------------------------------------------------------------------
// Kernel 1: grouped 4x4/s4 conv + BN(eval) + ReLU6 -> t[B][196][128]
// ---------------------------------------------------------------------------
__global__ __launch_bounds__(256) void conv_embed_kernel(
    const float* __restrict__ x, const float* __restrict__ cw,
    const float* __restrict__ cb, const float* __restrict__ gam,
    const float* __restrict__ bet, const float* __restrict__ mea,
    const float* __restrict__ var, float* __restrict__ tbuf)
{
  __shared__ __align__(16) float xs[12544];
  __shared__ __align__(16) float wsm[64];
  const int c = blockIdx.x, b = blockIdx.y, tid = threadIdx.x;
  const float4* xb = (const float4*)(x + (b*512 + 4*c)*3136);
  for (int t = tid; t < 3136; t += 256) ((float4*)xs)[t] = xb[t];
  if (tid < 64) wsm[tid] = cw[c*64 + tid];
  __syncthreads();
  if (tid < 196) {
    int oy = tid / 14, ox = tid - (tid/14)*14;
    float acc = cb[c];
#pragma unroll
    for (int i = 0; i < 4; ++i)
#pragma unroll
      for (int kh = 0; kh < 4; ++kh) {
        float4 xv = *(const float4*)&xs[i*3136 + (4*oy+kh)*56 + 4*ox];
        float4 wv = *(const float4*)&wsm[i*16 + kh*4];
        acc += xv.x*wv.x + xv.y*wv.y + xv.z*wv.z + xv.w*wv.w;
      }
    float sc = gam[c] * rsqrtf(var[c] + 1e-5f);
    float v = acc*sc + (bet[c] - mea[c]*sc);
    v = fminf(fmaxf(v, 0.0f), 6.0f);
    tbuf[(b*196 + tid)*128 + c] = v;
  }
}

// ---------------------------------------------------------------------------
// Kernel 2: fold proj into convout:  Wc[512][128] = convout_w @ proj_w,
//           bias_c[512] = convout_w @ proj_b + convout_b
// ---------------------------------------------------------------------------
__global__ __launch_bounds__(256) void make_wc_kernel(
    const float* __restrict__ cow, const float* __restrict__ pw,
    const float* __restrict__ pb, const float* __restrict__ cob,
    float* __restrict__ Wc, float* __restrict__ bias_c)
{
  int idx = blockIdx.x*256 + threadIdx.x;     // 65536 = 512*128
  int oc = idx >> 7, k = idx & 127;
  float acc = 0.f;
  for (int cc = 0; cc < 128; ++cc) acc += cow[oc*128 + cc] * pw[cc*128 + k];
  Wc[idx] = acc;
  if (blockIdx.x < 2) {                       // first 512 threads also do bias
    float a2 = cob[idx];
    for (int cc = 0; cc < 128; ++cc) a2 += cow[idx*128 + cc] * pb[cc];
    bias_c[idx] = a2;
  }
}

// ---------------------------------------------------------------------------
// Shared 64x64 tile GEMM core (K=128): k-major LDS, stride 68
// ---------------------------------------------------------------------------
__device__ __forceinline__ void gemm_tile_64x64(
    const float* __restrict__ Ag, const float* __restrict__ Bg,
    int row0, int col0, float* As, float* Bs, float (&acc)[4][4])
{
  const int tid = threadIdx.x;
#pragma unroll
  for (int it = 0; it < 8; ++it) {
    int rr = (it & 3)*16 + (tid & 15);
    int kq = (it >> 2)*16 + (tid >> 4);
    float4 va = *(const float4*)&Ag[(row0+rr)*128 + kq*4];
    As[(4*kq+0)*68 + rr] = va.x;
    As[(4*kq+1)*68 + rr] = va.y;
    As[(4*kq+2)*68 + rr] = va.z;
    As[(4*kq+3)*68 + rr] = va.w;
    float4 vb = *(const float4*)&Bg[(col0+rr)*128 + kq*4];
    Bs[(4*kq+0)*68 + rr] = vb.x;
    Bs[(4*kq+1)*68 + rr] = vb.y;
    Bs[(4*kq+2)*68 + rr] = vb.z;
    Bs[(4*kq+3)*68 + rr] = vb.w;
  }
  __syncthreads();
  const int tx = (tid & 15)*4, ty = (tid >> 4)*4;
#pragma unroll 8
  for (int k = 0; k < 128; ++k) {
    float4 a4 = *(const float4*)&As[k*68 + ty];
    float4 b4 = *(const float4*)&Bs[k*68 + tx];
    float av[4] = {a4.x, a4.y, a4.z, a4.w};
    float bv[4] = {b4.x, b4.y, b4.z, b4.w};
#pragma unroll
    for (int i = 0; i < 4; ++i)
#pragma unroll
      for (int j = 0; j < 4; ++j) acc[i][j] += av[i]*bv[j];
  }
}

// ---------------------------------------------------------------------------
// Kernel 3: qkv = t @ qkv_w^T, scattered to [s][b][h][n][d], q pre-scaled
// ---------------------------------------------------------------------------
__global__ __launch_bounds__(256) void gemm_qkv_kernel(
    const float* __restrict__ t, const float* __restrict__ qkv_w,
    float* __restrict__ qkv)
{
  __shared__ __align__(16) float As[128*68];
  __shared__ __align__(16) float Bs[128*68];
  float acc[4][4] = {};
  gemm_tile_64x64(t, qkv_w, blockIdx.y*64, blockIdx.x*64, As, Bs, acc);
  const int tid = threadIdx.x;
  const int tx = (tid & 15)*4, ty = (tid >> 4)*4;
  const int col0 = blockIdx.x*64 + tx;        // multiple of 4, quad within one 32-blk
  const int s3 = col0 >> 7, rr = col0 & 127;
  const int hh = rr >> 5, dd = rr & 31;
  const float qs = (s3 == 0) ? QSCALE : 1.0f;
#pragma unroll
  for (int i = 0; i < 4; ++i) {
    int row = blockIdx.y*64 + ty + i;
    int bb = row / 196, nn = row - bb*196;
    float4 v;
    v.x = acc[i][0]*qs; v.y = acc[i][1]*qs; v.z = acc[i][2]*qs; v.w = acc[i][3]*qs;
    *(float4*)&qkv[(((s3*32 + bb)*4 + hh)*196 + nn)*32 + dd] = v;
  }
}

// ---------------------------------------------------------------------------
// Kernel 4 (fused score+softmax+PV): flash attention, S never leaves regs.
// grid (2, 4, 32) = (q-half, h, b), 256 threads.
// Lane pair (2r, 2r+1) owns q-row n = qhalf*98 + r; each lane covers half
// the key range (98 keys), merged at the end via shfl_xor(1).
// ---------------------------------------------------------------------------
__global__ __launch_bounds__(256) void attn_kernel(
    const float* __restrict__ qkv, const float* __restrict__ rpb,
    float* __restrict__ o)
{
  __shared__ __align__(16) float k_lds[196*32];   // 25088 B
  __shared__ __align__(16) float v_lds[196*32];   // 25088 B
  __shared__ float rpb_lds[729];
  __shared__ int   off_lds[196];
  const int qhalf = blockIdx.x, h = blockIdx.y, b = blockIdx.z;
  const int tid = threadIdx.x;
  const float4* kg = (const float4*)(qkv + ((32 + b)*4 + h)*6272);
  const float4* vg = (const float4*)(qkv + ((64 + b)*4 + h)*6272);
  for (int t = tid; t < 1568; t += 256) {
    ((float4*)k_lds)[t] = kg[t];
    ((float4*)v_lds)[t] = vg[t];
  }
  for (int t = tid; t < 729; t += 256) rpb_lds[t] = rpb[t*4 + h];
  if (tid < 196) { int y = tid/14; off_lds[tid] = y*27 + (tid - y*14); }

  const int r = tid >> 1, half = tid & 1;
  const bool act = (r < 98);
  const int n = qhalf*98 + (act ? r : 0);
  // q row in registers (q already pre-scaled by QSCALE in gemm_qkv)
  const float4* qg = (const float4*)(qkv + ((b*4 + h)*196 + n)*32);
  float4 qv[8];
#pragma unroll
  for (int d = 0; d < 8; ++d) qv[d] = qg[d];
  const int yn = n/14, xn = n - yn*14;
  const int basen = yn*27 + xn + 364;          // idx = basen - (ym*27+xm)
  __syncthreads();

  float mx = -1e30f, sum = 0.f;
  float4 oa[8];
#pragma unroll
  for (int d = 0; d < 8; ++d) oa[d] = make_float4(0.f, 0.f, 0.f, 0.f);
  const int m0 = half*98;
#pragma unroll 2
  for (int i = 0; i < 98; ++i) {
    const int m = m0 + i;
    const float4* kr = (const float4*)&k_lds[m*32];
    float sx = 0.f, sy = 0.f, sz = 0.f, sw = 0.f;   // 4 indep chains
#pragma unroll
    for (int d = 0; d < 8; ++d) {
      float4 kv = kr[d];
      sx += qv[d].x*kv.x; sy += qv[d].y*kv.y;
      sz += qv[d].z*kv.z; sw += qv[d].w*kv.w;
    }
    float s = (sx + sy) + (sz + sw) + rpb_lds[basen - off_lds[m]];
    if (s > mx + 4.f) {                              // deferred-max rescale
      float sc = __expf(mx - s);
      sum *= sc;
#pragma unroll
      for (int d = 0; d < 8; ++d) {
        oa[d].x *= sc; oa[d].y *= sc; oa[d].z *= sc; oa[d].w *= sc;
      }
      mx = s;
    }
    float e = __expf(s - mx);
    sum += e;
    const float4* vr = (const float4*)&v_lds[m*32];
#pragma unroll
    for (int d = 0; d < 8; ++d) {
      float4 vv = vr[d];
      oa[d].x += e*vv.x; oa[d].y += e*vv.y;
      oa[d].z += e*vv.z; oa[d].w += e*vv.w;
    }
  }
  // merge the two half-range lanes of the pair
  float omx  = __shfl_xor(mx, 1);
  float osum = __shfl_xor(sum, 1);
  float M = fmaxf(mx, omx);
  float sa = __expf(mx - M), sb = __expf(omx - M);
  float inv = 1.f / (sum*sa + osum*sb);
  sa *= inv; sb *= inv;
#pragma unroll
  for (int d = 0; d < 8; ++d) {
    float px = __shfl_xor(oa[d].x, 1);
    float py = __shfl_xor(oa[d].y, 1);
    float pz = __shfl_xor(oa[d].z, 1);
    float pw = __shfl_xor(oa[d].w, 1);
    oa[d].x = oa[d].x*sa + px*sb;
    oa[d].y = oa[d].y*sa + py*sb;
    oa[d].z = oa[d].z*sa + pz*sb;
    oa[d].w = oa[d].w*sa + pw*sb;
  }
  if (act && half == 0) {
    float4* op = (float4*)&o[(b*196 + n)*128 + h*32];
#pragma unroll
    for (int d = 0; d < 8; ++d) op[d] = oa[d];
  }
}

// ---------------------------------------------------------------------------
// Kernel 5: fused proj+convout:  co[b][oc][n] = Wc[oc] . o[b][n] + bias_c[oc]
// ---------------------------------------------------------------------------
__global__ __launch_bounds__(256) void gemm_out_kernel(
    const float* __restrict__ obuf, const float* __restrict__ Wc,
    const float* __restrict__ bias_c, float* __restrict__ co)
{
  __shared__ __align__(16) float As[128*68];
  __shared__ __align__(16) float Bs[128*68];
  float acc[4][4] = {};
  gemm_tile_64x64(obuf, Wc, blockIdx.y*64, blockIdx.x*64, As, Bs, acc);
  const int tid = threadIdx.x;
  const int tx = (tid & 15)*4, ty = (tid >> 4)*4;
  const int row0 = blockIdx.y*64 + ty;        // multiple of 4; 196%4==0 -> same bb
  const int bb = row0 / 196, nn0 = row0 - bb*196;
#pragma unroll
  for (int j = 0; j < 4; ++j) {
    int col = blockIdx.x*64 + tx + j;
    float bc = bias_c[col];
    float4 v;
    v.x = acc[0][j] + bc; v.y = acc[1][j] + bc;
    v.z = acc[2][j] + bc; v.w = acc[3][j] + bc;
    *(float4*)&co[(bb*512 + col)*196 + nn0] = v;
  }
}

// ---------------------------------------------------------------------------
// Kernel 6: bilinear x4 upsample (align_corners) 14x14 -> 56x56
// ---------------------------------------------------------------------------
__global__ __launch_bounds__(256) void upsample_kernel(
    const float* __restrict__ co, float* __restrict__ out)
{
  __shared__ float cs[1568];
  __shared__ int lo_s[56];
  __shared__ float w_s[56];
  const int cg = blockIdx.x, b = blockIdx.y, tid = threadIdx.x;
  const float* cbase = co + (b*512 + cg*8)*196;
  for (int t = tid; t < 1568; t += 256) cs[t] = cbase[t];
  if (tid < 56) {
    double s = (double)(tid*13) / 55.0;
    int lo = (int)s;
    lo_s[tid] = lo;
    w_s[tid] = (float)(s - lo);
  }
  __syncthreads();
  float* obase = out + (b*512 + cg*8)*3136;
  for (int t4 = tid; t4 < 6272; t4 += 256) {
    int ch = t4 / 784;
    int rem = t4 - ch*784;
    int i2 = rem / 14;
    int j4 = (rem - i2*14)*4;
    int li = lo_s[i2]; float wi = w_s[i2];
    int hi = (li+1 < 13) ? li+1 : 13;
    const float* p0 = cs + ch*196 + li*14;
    const float* p1 = cs + ch*196 + hi*14;
    float4 ov;
    float* ovp = (float*)&ov;
#pragma unroll
    for (int jj = 0; jj < 4; ++jj) {
      int j2 = j4 + jj;
      int lj = lo_s[j2]; float wj = w_s[j2];
      int hj = (lj+1 < 13) ? lj+1 : 13;
      float top = p0[lj]*(1.f-wj) + p0[hj]*wj;
      float bot = p1[lj]*(1.f-wj) + p1[hj]*wj;
      ovp[jj] = top*(1.f-wi) + bot*wi;
    }
    ((float4*)obase)[t4] = ov;
  }
}

// ---------------------------------------------------------------------------
extern "C" void kernel_launch(void* const* d_in, const int* in_sizes, int n_in,
                              void* d_out, int out_size, void* d_ws, size_t ws_size,
                              hipStream_t stream)
{
  const float* x         = (const float*)d_in[0];
  const float* conv_w    = (const float*)d_in[1];
  const float* conv_b    = (const float*)d_in[2];
  const float* bn_gamma  = (const float*)d_in[3];
  const float* bn_beta   = (const float*)d_in[4];
  const float* bn_mean   = (const float*)d_in[5];
  const float* bn_var    = (const float*)d_in[6];
  const float* qkv_w     = (const float*)d_in[7];
  const float* proj_w    = (const float*)d_in[8];
  const float* proj_b    = (const float*)d_in[9];
  const float* rpb       = (const float*)d_in[10];
  const float* convout_w = (const float*)d_in[11];
  const float* convout_b = (const float*)d_in[12];
  float* out = (float*)d_out;
  float* ws  = (float*)d_ws;

  // workspace layout (floats); St eliminated by fused attention
  float* tbuf   = ws;                // 802816   [B,196,128]
  float* qkvb   = ws + 802816;       // 2408448  [3,B,4,196,32]
  float* obuf   = ws + 3211264;      // 802816   [B,196,128]
  float* Wc     = ws + 4014080;      // 65536    [512,128]
  float* bias_c = ws + 4079616;      // 512
  float* co     = ws + 4080128;      // 3211264  [B,512,196]

  conv_embed_kernel<<<dim3(128, 32), 256, 0, stream>>>(
      x, conv_w, conv_b, bn_gamma, bn_beta, bn_mean, bn_var, tbuf);
  make_wc_kernel<<<dim3(256), 256, 0, stream>>>(
      convout_w, proj_w, proj_b, convout_b, Wc, bias_c);
  gemm_qkv_kernel<<<dim3(6, 98), 256, 0, stream>>>(tbuf, qkv_w, qkvb);
  attn_kernel<<<dim3(2, 4, 32), 256, 0, stream>>>(qkvb, rpb, obuf);
  gemm_out_kernel<<<dim3(8, 98), 256, 0, stream>>>(obuf, Wc, bias_c, co);
  upsample_kernel<<<dim3(64, 32), 256, 0, stream>>>(co, out);
}

// Round 2
// 464.393 us; speedup vs baseline: 1.0849x; 1.0379x over previous
//
#include <hip/hip_runtime.h>

// Problem constants: B=32, DIM=512, C=128, NH=4, HD=32, WS=14, N=196, H_IN=56
#define QSCALE 0.17677669529663687f   // 32^-0.5

typedef __attribute__((ext_vector_type(8))) short bf16x8;
typedef __attribute__((ext_vector_type(4))) float f32x4;

// ---------------------------------------------------------------------------
// Kernel 1: grouped 4x4/s4 conv + BN(eval) + ReLU6 -> t[B][196][128]
// ---------------------------------------------------------------------------
__global__ __launch_bounds__(256) void conv_embed_kernel(
    const float* __restrict__ x, const float* __restrict__ cw,
    const float* __restrict__ cb, const float* __restrict__ gam,
    const float* __restrict__ bet, const float* __restrict__ mea,
    const float* __restrict__ var, float* __restrict__ tbuf)
{
  __shared__ __align__(16) float xs[12544];
  __shared__ __align__(16) float wsm[64];
  const int c = blockIdx.x, b = blockIdx.y, tid = threadIdx.x;
  const float4* xb = (const float4*)(x + (b*512 + 4*c)*3136);
  for (int t = tid; t < 3136; t += 256) ((float4*)xs)[t] = xb[t];
  if (tid < 64) wsm[tid] = cw[c*64 + tid];
  __syncthreads();
  if (tid < 196) {
    int oy = tid / 14, ox = tid - (tid/14)*14;
    float acc = cb[c];
#pragma unroll
    for (int i = 0; i < 4; ++i)
#pragma unroll
      for (int kh = 0; kh < 4; ++kh) {
        float4 xv = *(const float4*)&xs[i*3136 + (4*oy+kh)*56 + 4*ox];
        float4 wv = *(const float4*)&wsm[i*16 + kh*4];
        acc += xv.x*wv.x + xv.y*wv.y + xv.z*wv.z + xv.w*wv.w;
      }
    float sc = gam[c] * rsqrtf(var[c] + 1e-5f);
    float v = acc*sc + (bet[c] - mea[c]*sc);
    v = fminf(fmaxf(v, 0.0f), 6.0f);
    tbuf[(b*196 + tid)*128 + c] = v;
  }
}

// ---------------------------------------------------------------------------
// Kernel 2: fold proj into convout:  Wc[512][128] = convout_w @ proj_w,
//           bias_c[512] = convout_w @ proj_b + convout_b
// ---------------------------------------------------------------------------
__global__ __launch_bounds__(256) void make_wc_kernel(
    const float* __restrict__ cow, const float* __restrict__ pw,
    const float* __restrict__ pb, const float* __restrict__ cob,
    float* __restrict__ Wc, float* __restrict__ bias_c)
{
  int idx = blockIdx.x*256 + threadIdx.x;     // 65536 = 512*128
  int oc = idx >> 7, k = idx & 127;
  float acc = 0.f;
  for (int cc = 0; cc < 128; ++cc) acc += cow[oc*128 + cc] * pw[cc*128 + k];
  Wc[idx] = acc;
  if (blockIdx.x < 2) {                       // first 512 threads also do bias
    float a2 = cob[idx];
    for (int cc = 0; cc < 128; ++cc) a2 += cow[idx*128 + cc] * pb[cc];
    bias_c[idx] = a2;
  }
}

// ---------------------------------------------------------------------------
// Split-bf16 MFMA GEMM helpers.
//   fp32 a = hi + lo (both bf16); a.b ~= hi.hi + hi.lo + lo.hi (lo.lo ~2^-18)
//   LDS planes: [64 rows][128 bf16], 16B blocks swizzled: slot = kb ^ (row&7)
// ---------------------------------------------------------------------------
__device__ __forceinline__ unsigned short f2bf(float f)
{
  unsigned u = __float_as_uint(f);
  u += 0x7fffu + ((u >> 16) & 1u);            // round-to-nearest-even
  return (unsigned short)(u >> 16);
}

__device__ __forceinline__ void stage64x128(
    const float* __restrict__ g, unsigned short* hi, unsigned short* lo, int tid)
{
#pragma unroll
  for (int i = 0; i < 8; ++i) {
    int idx4 = tid + i*256;                   // 0..2047 float4s
    int row = idx4 >> 5;
    int c4  = idx4 & 31;
    float4 v = *(const float4*)&g[idx4*4];
    ushort4 h, l;
    h.x = f2bf(v.x); h.y = f2bf(v.y); h.z = f2bf(v.z); h.w = f2bf(v.w);
    l.x = f2bf(v.x - __uint_as_float((unsigned)h.x << 16));
    l.y = f2bf(v.y - __uint_as_float((unsigned)h.y << 16));
    l.z = f2bf(v.z - __uint_as_float((unsigned)h.z << 16));
    l.w = f2bf(v.w - __uint_as_float((unsigned)h.w << 16));
    int slot = (c4 >> 1) ^ (row & 7);
    int uidx = row*128 + slot*8 + (c4 & 1)*4;
    *(ushort4*)&hi[uidx] = h;
    *(ushort4*)&lo[uidx] = l;
  }
}

__device__ __forceinline__ bf16x8 ldfrag(const unsigned short* p, int row, int kb)
{
  return *(const bf16x8*)&p[row*128 + (kb ^ (row & 7))*8];
}

// Core: 64x64 tile, K=128, 4 waves (wave w owns rows w*16..w*16+15).
// acc[f] is the 16x16 D-frag for cols f*16..f*16+15.
__device__ __forceinline__ void mfma_tile_64x64(
    const float* __restrict__ Ag, const float* __restrict__ Bg,
    unsigned short* Ahi, unsigned short* Alo,
    unsigned short* Bhi, unsigned short* Blo, f32x4 (&acc)[4])
{
  const int tid = threadIdx.x;
  stage64x128(Ag, Ahi, Alo, tid);
  stage64x128(Bg, Bhi, Blo, tid);
  __syncthreads();
  const int w = tid >> 6, l = tid & 63;
  const int lr = l & 15, lg = l >> 4;
#pragma unroll
  for (int s = 0; s < 4; ++s) {
    int kb = s*4 + lg;
    bf16x8 ah = ldfrag(Ahi, w*16 + lr, kb);
    bf16x8 al = ldfrag(Alo, w*16 + lr, kb);
#pragma unroll
    for (int f = 0; f < 4; ++f) {
      bf16x8 bh = ldfrag(Bhi, f*16 + lr, kb);
      bf16x8 bl = ldfrag(Blo, f*16 + lr, kb);
      acc[f] = __builtin_amdgcn_mfma_f32_16x16x32_bf16(ah, bh, acc[f], 0, 0, 0);
      acc[f] = __builtin_amdgcn_mfma_f32_16x16x32_bf16(ah, bl, acc[f], 0, 0, 0);
      acc[f] = __builtin_amdgcn_mfma_f32_16x16x32_bf16(al, bh, acc[f], 0, 0, 0);
    }
  }
}

// ---------------------------------------------------------------------------
// Kernel 3: qkv = t @ qkv_w^T (MFMA split-bf16), scatter to [s][b][h][n][d],
//           q pre-scaled. D-frag: col = lane&15, row = 4*(lane>>4)+r  [m89]
// ---------------------------------------------------------------------------
__global__ __launch_bounds__(256) void gemm_qkv_kernel(
    const float* __restrict__ t, const float* __restrict__ qkv_w,
    float* __restrict__ qkv)
{
  __shared__ __align__(16) unsigned short sm[32768];   // 64 KB
  unsigned short* Ahi = sm;
  unsigned short* Alo = sm + 8192;
  unsigned short* Bhi = sm + 16384;
  unsigned short* Blo = sm + 24576;
  const int m0 = blockIdx.y*64, n0 = blockIdx.x*64;
  f32x4 acc[4] = {};
  mfma_tile_64x64(t + m0*128, qkv_w + n0*128, Ahi, Alo, Bhi, Blo, acc);
  const int tid = threadIdx.x;
  const int w = tid >> 6, l = tid & 63;
  const int lr = l & 15, lg = l >> 4;
#pragma unroll
  for (int f = 0; f < 4; ++f) {
    int col = n0 + f*16 + lr;
    int s3 = col >> 7, rr = col & 127;
    int hh = rr >> 5, dd = rr & 31;
    float qs = (s3 == 0) ? QSCALE : 1.0f;
#pragma unroll
    for (int r = 0; r < 4; ++r) {
      int row = m0 + w*16 + lg*4 + r;
      int bb = row / 196, nn = row - bb*196;
      qkv[(((s3*32 + bb)*4 + hh)*196 + nn)*32 + dd] = acc[f][r]*qs;
    }
  }
}

// ---------------------------------------------------------------------------
// Kernel 4 (fused score+softmax+PV): flash attention, S never leaves regs.
// grid (2, 4, 32) = (q-half, h, b), 256 threads.
// ---------------------------------------------------------------------------
__global__ __launch_bounds__(256) void attn_kernel(
    const float* __restrict__ qkv, const float* __restrict__ rpb,
    float* __restrict__ o)
{
  __shared__ __align__(16) float k_lds[196*32];   // 25088 B
  __shared__ __align__(16) float v_lds[196*32];   // 25088 B
  __shared__ float rpb_lds[729];
  __shared__ int   off_lds[196];
  const int qhalf = blockIdx.x, h = blockIdx.y, b = blockIdx.z;
  const int tid = threadIdx.x;
  const float4* kg = (const float4*)(qkv + ((32 + b)*4 + h)*6272);
  const float4* vg = (const float4*)(qkv + ((64 + b)*4 + h)*6272);
  for (int t = tid; t < 1568; t += 256) {
    ((float4*)k_lds)[t] = kg[t];
    ((float4*)v_lds)[t] = vg[t];
  }
  for (int t = tid; t < 729; t += 256) rpb_lds[t] = rpb[t*4 + h];
  if (tid < 196) { int y = tid/14; off_lds[tid] = y*27 + (tid - y*14); }

  const int r = tid >> 1, half = tid & 1;
  const bool act = (r < 98);
  const int n = qhalf*98 + (act ? r : 0);
  const float4* qg = (const float4*)(qkv + ((b*4 + h)*196 + n)*32);
  float4 qv[8];
#pragma unroll
  for (int d = 0; d < 8; ++d) qv[d] = qg[d];
  const int yn = n/14, xn = n - yn*14;
  const int basen = yn*27 + xn + 364;
  __syncthreads();

  float mx = -1e30f, sum = 0.f;
  float4 oa[8];
#pragma unroll
  for (int d = 0; d < 8; ++d) oa[d] = make_float4(0.f, 0.f, 0.f, 0.f);
  const int m0 = half*98;
#pragma unroll 2
  for (int i = 0; i < 98; ++i) {
    const int m = m0 + i;
    const float4* kr = (const float4*)&k_lds[m*32];
    float sx = 0.f, sy = 0.f, sz = 0.f, sw = 0.f;
#pragma unroll
    for (int d = 0; d < 8; ++d) {
      float4 kv = kr[d];
      sx += qv[d].x*kv.x; sy += qv[d].y*kv.y;
      sz += qv[d].z*kv.z; sw += qv[d].w*kv.w;
    }
    float s = (sx + sy) + (sz + sw) + rpb_lds[basen - off_lds[m]];
    if (s > mx + 4.f) {
      float sc = __expf(mx - s);
      sum *= sc;
#pragma unroll
      for (int d = 0; d < 8; ++d) {
        oa[d].x *= sc; oa[d].y *= sc; oa[d].z *= sc; oa[d].w *= sc;
      }
      mx = s;
    }
    float e = __expf(s - mx);
    sum += e;
    const float4* vr = (const float4*)&v_lds[m*32];
#pragma unroll
    for (int d = 0; d < 8; ++d) {
      float4 vv = vr[d];
      oa[d].x += e*vv.x; oa[d].y += e*vv.y;
      oa[d].z += e*vv.z; oa[d].w += e*vv.w;
    }
  }
  float omx  = __shfl_xor(mx, 1);
  float osum = __shfl_xor(sum, 1);
  float M = fmaxf(mx, omx);
  float sa = __expf(mx - M), sb = __expf(omx - M);
  float inv = 1.f / (sum*sa + osum*sb);
  sa *= inv; sb *= inv;
#pragma unroll
  for (int d = 0; d < 8; ++d) {
    float px = __shfl_xor(oa[d].x, 1);
    float py = __shfl_xor(oa[d].y, 1);
    float pz = __shfl_xor(oa[d].z, 1);
    float pw = __shfl_xor(oa[d].w, 1);
    oa[d].x = oa[d].x*sa + px*sb;
    oa[d].y = oa[d].y*sa + py*sb;
    oa[d].z = oa[d].z*sa + pz*sb;
    oa[d].w = oa[d].w*sa + pw*sb;
  }
  if (act && half == 0) {
    float4* op = (float4*)&o[(b*196 + n)*128 + h*32];
#pragma unroll
    for (int d = 0; d < 8; ++d) op[d] = oa[d];
  }
}

// ---------------------------------------------------------------------------
// Kernel 5: fused proj+convout (MFMA split-bf16) with LDS-transpose epilogue
// so co[b][oc][n] writes stay nn-contiguous (coalesced float4).
// ---------------------------------------------------------------------------
__global__ __launch_bounds__(256) void gemm_out_kernel(
    const float* __restrict__ obuf, const float* __restrict__ Wc,
    const float* __restrict__ bias_c, float* __restrict__ co)
{
  __shared__ __align__(16) unsigned short sm[32768];   // 64 KB
  unsigned short* Ahi = sm;
  unsigned short* Alo = sm + 8192;
  unsigned short* Bhi = sm + 16384;
  unsigned short* Blo = sm + 24576;
  float* tr = (float*)sm;                    // aliases Ahi/Alo: 64*68*4 = 17.4 KB
  const int m0 = blockIdx.y*64, n0 = blockIdx.x*64;
  f32x4 acc[4] = {};
  mfma_tile_64x64(obuf + m0*128, Wc + n0*128, Ahi, Alo, Bhi, Blo, acc);
  const int tid = threadIdx.x;
  const int w = tid >> 6, l = tid & 63;
  const int lr = l & 15, lg = l >> 4;
  __syncthreads();                           // all frag reads done before alias
#pragma unroll
  for (int f = 0; f < 4; ++f)
#pragma unroll
    for (int r = 0; r < 4; ++r)
      tr[(w*16 + lg*4 + r)*68 + f*16 + lr] = acc[f][r];
  __syncthreads();
#pragma unroll
  for (int p = 0; p < 4; ++p) {
    int colL = p*16 + (tid >> 4);            // 0..63
    int nq = tid & 15;                       // 4-row quad (196%4==0: no b-cross)
    int rowG = m0 + nq*4;
    int bb = rowG / 196, nn = rowG - bb*196;
    float bc = bias_c[n0 + colL];
    float4 v;
    v.x = tr[(nq*4+0)*68 + colL] + bc;
    v.y = tr[(nq*4+1)*68 + colL] + bc;
    v.z = tr[(nq*4+2)*68 + colL] + bc;
    v.w = tr[(nq*4+3)*68 + colL] + bc;
    *(float4*)&co[(bb*512 + n0 + colL)*196 + nn] = v;
  }
}

// ---------------------------------------------------------------------------
// Kernel 6: bilinear x4 upsample (align_corners) 14x14 -> 56x56
// ---------------------------------------------------------------------------
__global__ __launch_bounds__(256) void upsample_kernel(
    const float* __restrict__ co, float* __restrict__ out)
{
  __shared__ float cs[1568];
  __shared__ int lo_s[56];
  __shared__ float w_s[56];
  const int cg = blockIdx.x, b = blockIdx.y, tid = threadIdx.x;
  const float* cbase = co + (b*512 + cg*8)*196;
  for (int t = tid; t < 1568; t += 256) cs[t] = cbase[t];
  if (tid < 56) {
    double s = (double)(tid*13) / 55.0;
    int lo = (int)s;
    lo_s[tid] = lo;
    w_s[tid] = (float)(s - lo);
  }
  __syncthreads();
  float* obase = out + (b*512 + cg*8)*3136;
  for (int t4 = tid; t4 < 6272; t4 += 256) {
    int ch = t4 / 784;
    int rem = t4 - ch*784;
    int i2 = rem / 14;
    int j4 = (rem - i2*14)*4;
    int li = lo_s[i2]; float wi = w_s[i2];
    int hi = (li+1 < 13) ? li+1 : 13;
    const float* p0 = cs + ch*196 + li*14;
    const float* p1 = cs + ch*196 + hi*14;
    float4 ov;
    float* ovp = (float*)&ov;
#pragma unroll
    for (int jj = 0; jj < 4; ++jj) {
      int j2 = j4 + jj;
      int lj = lo_s[j2]; float wj = w_s[j2];
      int hj = (lj+1 < 13) ? lj+1 : 13;
      float top = p0[lj]*(1.f-wj) + p0[hj]*wj;
      float bot = p1[lj]*(1.f-wj) + p1[hj]*wj;
      ovp[jj] = top*(1.f-wi) + bot*wi;
    }
    ((float4*)obase)[t4] = ov;
  }
}

// ---------------------------------------------------------------------------
extern "C" void kernel_launch(void* const* d_in, const int* in_sizes, int n_in,
                              void* d_out, int out_size, void* d_ws, size_t ws_size,
                              hipStream_t stream)
{
  const float* x         = (const float*)d_in[0];
  const float* conv_w    = (const float*)d_in[1];
  const float* conv_b    = (const float*)d_in[2];
  const float* bn_gamma  = (const float*)d_in[3];
  const float* bn_beta   = (const float*)d_in[4];
  const float* bn_mean   = (const float*)d_in[5];
  const float* bn_var    = (const float*)d_in[6];
  const float* qkv_w     = (const float*)d_in[7];
  const float* proj_w    = (const float*)d_in[8];
  const float* proj_b    = (const float*)d_in[9];
  const float* rpb       = (const float*)d_in[10];
  const float* convout_w = (const float*)d_in[11];
  const float* convout_b = (const float*)d_in[12];
  float* out = (float*)d_out;
  float* ws  = (float*)d_ws;

  float* tbuf   = ws;                // 802816   [B,196,128]
  float* qkvb   = ws + 802816;       // 2408448  [3,B,4,196,32]
  float* obuf   = ws + 3211264;      // 802816   [B,196,128]
  float* Wc     = ws + 4014080;      // 65536    [512,128]
  float* bias_c = ws + 4079616;      // 512
  float* co     = ws + 4080128;      // 3211264  [B,512,196]

  conv_embed_kernel<<<dim3(128, 32), 256, 0, stream>>>(
      x, conv_w, conv_b, bn_gamma, bn_beta, bn_mean, bn_var, tbuf);
  make_wc_kernel<<<dim3(256), 256, 0, stream>>>(
      convout_w, proj_w, proj_b, convout_b, Wc, bias_c);
  gemm_qkv_kernel<<<dim3(6, 98), 256, 0, stream>>>(tbuf, qkv_w, qkvb);
  attn_kernel<<<dim3(2, 4, 32), 256, 0, stream>>>(qkvb, rpb, obuf);
  gemm_out_kernel<<<dim3(8, 98), 256, 0, stream>>>(obuf, Wc, bias_c, co);
  upsample_kernel<<<dim3(64, 32), 256, 0, stream>>>(co, out);
}